// Round 7
// baseline (386.551 us; speedup 1.0000x reference)
//
#include <hip/hip_runtime.h>
#include <stdint.h>

#define S_LEN 2048
#define BATCH 2
#define HIDDEN 2560
#define NH 8
#define NKV 4
#define HD 256
#define QSZ (NH*HD)          // 2048
#define NQKV 4096            // QSZ + 2*KVSZ
#define MROWS (BATCH*S_LEN)  // 4096
#define SCALE_ATT 0.0625f

using bf16x8 = __attribute__((__ext_vector_type__(8))) __bf16;
using f32x4  = __attribute__((__ext_vector_type__(4))) float;
using s16x8  = __attribute__((__ext_vector_type__(8))) short;

union B8u { s16x8 s; bf16x8 b; };
union I4B8 { int4 i; bf16x8 b; };

__device__ __forceinline__ unsigned short f2bf(float x){
  unsigned u = __float_as_uint(x);
  u += 0x7fffu + ((u >> 16) & 1u);
  return (unsigned short)(u >> 16);
}
__device__ __forceinline__ float bf2f(unsigned short h){
  return __uint_as_float(((unsigned)h) << 16);
}
__device__ __forceinline__ bf16x8 ld_bf8(const unsigned short* p){
  B8u u; u.s = *reinterpret_cast<const s16x8*>(p); return u.b;
}
__device__ __forceinline__ f32x4 mfma16(bf16x8 a, bf16x8 b, f32x4 c){
  return __builtin_amdgcn_mfma_f32_16x16x32_bf16(a, b, c, 0, 0, 0);
}
__device__ __forceinline__ void gload16(const void* g, void* l){
  __builtin_amdgcn_global_load_lds((const __attribute__((address_space(1))) void*)g,
                                   (__attribute__((address_space(3))) void*)l,
                                   16, 0, 0);
}
__device__ __forceinline__ int cvtpk(float lo, float hi){
  int r;
  asm("v_cvt_pk_bf16_f32 %0, %1, %2" : "=v"(r) : "v"(lo), "v"(hi));
  return r;
}

// ---------------- cast fp32 -> bf16 (flat) ----------------
__global__ __launch_bounds__(256) void cast_bf16_kernel(
    const float* __restrict__ in, unsigned short* __restrict__ out, int n)
{
  int i = (blockIdx.x * 256 + threadIdx.x) * 4;
  if (i < n){
    float4 v = *reinterpret_cast<const float4*>(in + i);
    ushort4 o;
    o.x = f2bf(v.x); o.y = f2bf(v.y); o.z = f2bf(v.z); o.w = f2bf(v.w);
    *reinterpret_cast<ushort4*>(out + i) = o;
  }
}

// ---------------- transpose + cast: in[R][C] fp32 -> out[C][R] bf16 ----------------
__global__ __launch_bounds__(256) void tcast_kernel(
    const float* __restrict__ in, unsigned short* __restrict__ out, int R, int C)
{
  __shared__ float t[32][33];
  int c0 = blockIdx.x * 32, r0 = blockIdx.y * 32;
  int tx = threadIdx.x & 31, ty = threadIdx.x >> 5;
#pragma unroll
  for (int ii = 0; ii < 4; ii++)
    t[ty + ii*8][tx] = in[(size_t)(r0 + ty + ii*8) * C + c0 + tx];
  __syncthreads();
#pragma unroll
  for (int ii = 0; ii < 4; ii++)
    out[(size_t)(c0 + ty + ii*8) * R + r0 + tx] = f2bf(t[tx][ty + ii*8]);
}

// ================= 256x256 8-wave deep-pipelined GEMM (T2+T3+T4+T5) =================
// C[M][N] = A[M][K] * BT[N][K]^T, BK=64, 512 threads, 1 block/CU (128KB LDS).
// BF16OUT: write bf16 output (for qkv intermediate), else f32.
template<int BF16OUT>
__global__ __launch_bounds__(512, 2) void gemm256_kernel(
    const unsigned short* __restrict__ A,
    const unsigned short* __restrict__ BT,
    void* __restrict__ Cv,
    int N, int K, int nbn)
{
  __shared__ unsigned short Ab[2][256 * 64];
  __shared__ unsigned short Bb[2][256 * 64];

  const int tid  = threadIdx.x;
  const int lane = tid & 63;
  const int wid  = tid >> 6;            // 0..7
  const int wm = wid >> 2, wn = wid & 3;
  const int lq = lane & 15, lk = lane >> 4;

  // bijective XCD swizzle (gridDim.x % 8 == 0)
  const int cpx = gridDim.x >> 3;
  const int wg  = (blockIdx.x & 7) * cpx + (blockIdx.x >> 3);
  const int bm = wg / nbn, bn = wg % nbn;

  // staging source (pre-swizzled global -> linear LDS dest; involution slot^=(row&7))
  const int l8 = lane >> 3;                       // 0..7 (row within 8-row chunk)
  const int sl = ((lane & 7) ^ l8) * 8;           // pre-swizzled 16B slot
  const unsigned short* agS = A  + (size_t)(bm*256 + wid*16 + l8) * K + sl;
  const unsigned short* bgS = BT + (size_t)(bn*256 + wid*16 + l8) * K + sl;

  f32x4 acc[4][4][2] = {};
  bf16x8 a[4][2], b[2][2];

#define STA(c, h, tt) do {                                                    \
    unsigned short* d = &Ab[c][(h)*8192 + wid*1024];                          \
    const unsigned short* s = agS + (size_t)(h)*128*K + (size_t)(tt)*64;      \
    gload16(s, d); gload16(s + 8*(size_t)K, d + 512);                         \
  } while (0)
#define STB(c, h, tt) do {                                                    \
    unsigned short* d = &Bb[c][(h)*8192 + wid*1024];                          \
    const unsigned short* s = bgS + (size_t)(h)*128*K + (size_t)(tt)*64;      \
    gload16(s, d); gload16(s + 8*(size_t)K, d + 512);                         \
  } while (0)
#define LDA(qa) do {                                                          \
    _Pragma("unroll") for (int m = 0; m < 4; m++)                             \
    _Pragma("unroll") for (int kk = 0; kk < 2; kk++)                          \
      a[m][kk] = ld_bf8(&Ab[cur][((qa)*128 + wm*64 + m*16 + lq)*64            \
                                 + (((kk*4 + lk) ^ (lq & 7)) << 3)]);         \
  } while (0)
#define LDB(qb) do {                                                          \
    _Pragma("unroll") for (int n = 0; n < 2; n++)                             \
    _Pragma("unroll") for (int kk = 0; kk < 2; kk++)                          \
      b[n][kk] = ld_bf8(&Bb[cur][((qb)*128 + wn*32 + n*16 + lq)*64            \
                                 + (((kk*4 + lk) ^ (lq & 7)) << 3)]);         \
  } while (0)
#define MM(qi) do {                                                           \
    __builtin_amdgcn_s_setprio(1);                                            \
    _Pragma("unroll") for (int m = 0; m < 4; m++)                             \
    _Pragma("unroll") for (int n = 0; n < 2; n++)                             \
    _Pragma("unroll") for (int kk = 0; kk < 2; kk++)                          \
      acc[qi][m][n] = mfma16(a[m][kk], b[n][kk], acc[qi][m][n]);              \
    __builtin_amdgcn_s_setprio(0);                                            \
  } while (0)
#define BARR __builtin_amdgcn_s_barrier()
#define VM(n) asm volatile("s_waitcnt vmcnt(" #n ")" ::: "memory")

  // prologue: tile 0, issue order A0,B0,B1,A1; first two halves must land
  STA(0, 0, 0); STB(0, 0, 0); STB(0, 1, 0); STA(0, 1, 0);
  VM(4); BARR;

  const int NT = K >> 6;
  for (int t = 0; t < NT - 1; ++t){
    const int cur = t & 1, nxt = cur ^ 1;
    LDA(0); LDB(0); STA(nxt, 0, t+1);
    BARR; MM(0); VM(4); BARR;
    LDB(1);         STB(nxt, 0, t+1);
    BARR; MM(1); VM(4); BARR;
    LDA(1);         STB(nxt, 1, t+1);
    BARR; MM(2);        BARR;
    LDB(0);         STA(nxt, 1, t+1);
    BARR; MM(3); VM(4); BARR;
  }
  { // final tile: no staging; drain progressively
    const int cur = (NT - 1) & 1;
    LDA(0); LDB(0); BARR; MM(0); VM(2); BARR;
    LDB(1);         BARR; MM(1); VM(0); BARR;
    LDA(1);         BARR; MM(2);        BARR;
    LDB(0);         BARR; MM(3);        BARR;
  }
#undef STA
#undef STB
#undef LDA
#undef LDB
#undef MM
#undef BARR
#undef VM

  // epilogue: qi -> (qa, qb) = (qi>>1, gray(qi))
#pragma unroll
  for (int qi = 0; qi < 4; qi++){
    const int qa = qi >> 1;
    const int qb = (qi ^ (qi >> 1)) & 1;
    const int r0 = bm*256 + qa*128 + wm*64;
    const int c0 = bn*256 + qb*128 + wn*32;
#pragma unroll
    for (int m = 0; m < 4; m++)
#pragma unroll
      for (int n = 0; n < 2; n++)
#pragma unroll
        for (int i = 0; i < 4; i++){
          const size_t idx = (size_t)(r0 + m*16 + lk*4 + i) * N + (c0 + n*16 + lq);
          if (BF16OUT) ((unsigned short*)Cv)[idx] = f2bf(acc[qi][m][n][i]);
          else         ((float*)Cv)[idx]          = acc[qi][m][n][i];
        }
  }
}

// ---------------- RMSNorm + RoPE + scatter to q/k/vT (qkv now bf16) ----------------
__global__ __launch_bounds__(256) void normrope_kernel(
    const unsigned short* __restrict__ qkv,
    const int* __restrict__ positions,
    const float* __restrict__ qw, const float* __restrict__ kw,
    unsigned short* __restrict__ qB,
    unsigned short* __restrict__ kB,
    unsigned short* __restrict__ vT)
{
  const int s = blockIdx.x, b = blockIdx.y;
  const int lane = threadIdx.x & 63, wid = threadIdx.x >> 6;
  const unsigned short* row = qkv + (size_t)(b * S_LEN + s) * NQKV;
  const float fpos = (float)positions[b * S_LEN + s];

#pragma unroll
  for (int t = 0; t < 4; t++){
    const int seg = t * 4 + wid;
    const int base = seg * HD;
    float x0 = bf2f(row[base + lane]);
    float x1 = bf2f(row[base + lane + 64]);
    float x2 = bf2f(row[base + lane + 128]);
    float x3 = bf2f(row[base + lane + 192]);
    if (seg >= 12){
      const int mh = seg - 12;
      unsigned short* vb = vT + (size_t)(b * NKV + mh) * HD * S_LEN + s;
      vb[(size_t)(lane      ) * S_LEN] = f2bf(x0);
      vb[(size_t)(lane +  64) * S_LEN] = f2bf(x1);
      vb[(size_t)(lane + 128) * S_LEN] = f2bf(x2);
      vb[(size_t)(lane + 192) * S_LEN] = f2bf(x3);
    } else {
      const float* w = (seg < 8) ? qw : kw;
      float ssq = x0*x0 + x1*x1 + x2*x2 + x3*x3;
#pragma unroll
      for (int d = 1; d < 64; d <<= 1) ssq += __shfl_xor(ssq, d, 64);
      float rs = rsqrtf(ssq * (1.0f / 256.0f) + 1e-6f);
      float y0 = x0 * rs * (1.0f + w[lane]);
      float y1 = x1 * rs * (1.0f + w[lane + 64]);
      float y2 = x2 * rs * (1.0f + w[lane + 128]);
      float y3 = x3 * rs * (1.0f + w[lane + 192]);
      const float kln = -9.210340371976184f / 128.0f;
      float inv1 = expf((float)lane * kln);
      float inv2 = expf((float)(lane + 64) * kln);
      float s1, c1, s2, c2;
      sincosf(fpos * inv1, &s1, &c1);
      sincosf(fpos * inv2, &s2, &c2);
      float o0 = y0 * c1 - y2 * s1;
      float o2 = y2 * c1 + y0 * s1;
      float o1 = y1 * c2 - y3 * s2;
      float o3 = y3 * c2 + y1 * s2;
      unsigned short* dst = (seg < 8)
        ? qB + ((size_t)(b * NH  +  seg     ) * S_LEN + s) * HD
        : kB + ((size_t)(b * NKV + (seg - 8)) * S_LEN + s) * HD;
      dst[lane      ] = f2bf(o0);
      dst[lane +  64] = f2bf(o1);
      dst[lane + 128] = f2bf(o2);
      dst[lane + 192] = f2bf(o3);
    }
  }
}

// ---------------- attention-mask bit pack: bm[b][tile] = 32 valid bits ----------------
__global__ void maskbits_kernel(const int* __restrict__ amask, unsigned* __restrict__ bm)
{
  int t = threadIdx.x;                 // 0..127
  int b = t >> 6, tile = t & 63;
  unsigned m = 0;
  for (int j = 0; j < 32; j++)
    m |= (amask[b * S_LEN + tile * 32 + j] != 0 ? 1u : 0u) << j;
  bm[t] = m;
}

// ---------------- flash attention v6: balanced qt pairing ----------------
// grid 512, combo = id&7 -> XCD; j = id>>3; qt = (j<32)? 63-2j : 2(j-32) so
// co-resident blocks (j, j+32) have qt sums == 63 -> constant per-CU work.
__global__ __launch_bounds__(256) void attn_kernel(
    const unsigned short* __restrict__ qB,
    const unsigned short* __restrict__ kB,
    const unsigned short* __restrict__ vT,
    const unsigned* __restrict__ bmG,
    unsigned short* __restrict__ attnO)
{
  __shared__ unsigned short Kb[2][32 * 256];    // [key][d-granule ^ (key&7)], 16KB/buf
  __shared__ unsigned short Vb[2][256 * 32];    // [d][key-chunk ^ ((d>>1)&3)], 16KB/buf
  __shared__ unsigned bm_lds[64];

  const int tid  = threadIdx.x;
  const int lane = tid & 63, wid = tid >> 6;
  const int id = blockIdx.x;
  const int mh = id & 3, b = (id >> 2) & 1;
  const int j  = id >> 3;
  const int qt = (j < 32) ? (63 - 2*j) : (2*(j - 32));   // balanced pairing
  const int h  = mh * 2 + (wid >> 1);
  const int q0 = qt * 32 + (wid & 1) * 16;
  const int lq = lane & 15, lk = lane >> 4;
  const int q  = q0 + lq;

  const unsigned short* qbase = qB + ((size_t)(b * NH + h) * S_LEN + q0 + lq) * HD + lk * 8;
  bf16x8 aq[8];
#pragma unroll
  for (int ks = 0; ks < 8; ks++) aq[ks] = ld_bf8(qbase + ks * 32);

  if (tid < 64) bm_lds[tid] = bmG[(b << 6) + tid];

  const unsigned short* kbase = kB + (size_t)(b * NKV + mh) * S_LEN * HD;
  const unsigned short* vbase = vT + (size_t)(b * NKV + mh) * HD * S_LEN;
  const int krow0 = wid * 2 + (lane >> 5);
  const int kgsrc = (lane & 31) ^ (krow0 & 7);
  const unsigned short* kg0 = kbase + (size_t)krow0 * HD + kgsrc * 8;
  const int vd0 = wid * 16 + (lane >> 2);
  const int vgsrc = (lane & 3) ^ ((lane >> 3) & 3);
  const unsigned short* vg0 = vbase + (size_t)vd0 * S_LEN + vgsrc * 8;

  asm volatile("s_waitcnt vmcnt(0)" ::: "memory");

  float mi = -__builtin_inff(), li = 0.f;
  f32x4 oacc[16] = {};

  const int ktmax = qt * 32;

#define STAGE_K(buf, ktv)                                                      \
  do {                                                                         \
    _Pragma("unroll")                                                          \
    for (int r = 0; r < 4; r++)                                                \
      gload16(kg0 + (size_t)(ktv) * HD + r * (8 * HD),                         \
              &Kb[buf][wid * 512 + r * 2048]);                                 \
  } while (0)
#define STAGE_V(buf, ktv)                                                      \
  do {                                                                         \
    _Pragma("unroll")                                                          \
    for (int r = 0; r < 4; r++)                                                \
      gload16(vg0 + (ktv) + (size_t)r * (64 * S_LEN),                          \
              &Vb[buf][wid * 512 + r * 2048]);                                 \
  } while (0)

  STAGE_K(0, 0);  STAGE_V(0, 0);
  if (ktmax >= 32){ STAGE_K(1, 32); STAGE_V(1, 32); }

  int cur = 0;
  for (int kt = 0; kt <= ktmax; kt += 32, cur ^= 1){
    if (kt < ktmax) asm volatile("s_waitcnt vmcnt(8)" ::: "memory");
    else            asm volatile("s_waitcnt vmcnt(0)" ::: "memory");
    __syncthreads();

    f32x4 s0 = {0.f,0.f,0.f,0.f}, s1 = {0.f,0.f,0.f,0.f};
#pragma unroll
    for (int ks = 0; ks < 8; ks++){
      const int slot = (((ks * 4 + lk) ^ (lq & 7)) << 3);
      bf16x8 kf0 = ld_bf8(&Kb[cur][lq * 256 + slot]);
      bf16x8 kf1 = ld_bf8(&Kb[cur][(16 + lq) * 256 + slot]);
      s0 = mfma16(kf0, aq[ks], s0);
      s1 = mfma16(kf1, aq[ks], s1);
    }

    const unsigned mask32 = bm_lds[kt >> 5];
    const int koff = lk * 4;
    float v0[4], v1[4];
#pragma unroll
    for (int j2 = 0; j2 < 4; j2++){
      const bool c0 = (kt + koff + j2 <= q)      && ((mask32 >> (koff + j2)) & 1u);
      const bool c1 = (kt + 16 + koff + j2 <= q) && ((mask32 >> (16 + koff + j2)) & 1u);
      v0[j2] = c0 ? s0[j2] * SCALE_ATT : -__builtin_inff();
      v1[j2] = c1 ? s1[j2] * SCALE_ATT : -__builtin_inff();
    }
    float tm = fmaxf(fmaxf(fmaxf(v0[0], v0[1]), fmaxf(v0[2], v0[3])),
                     fmaxf(fmaxf(v1[0], v1[1]), fmaxf(v1[2], v1[3])));
    tm = fmaxf(tm, __shfl_xor(tm, 16, 64));
    tm = fmaxf(tm, __shfl_xor(tm, 32, 64));

    float p0[4], p1[4];
    if (__all(tm <= mi + 8.0f)){
      const float mns = fmaxf(mi, -1e30f);
#pragma unroll
      for (int j2 = 0; j2 < 4; j2++){
        p0[j2] = __expf(v0[j2] - mns);
        p1[j2] = __expf(v1[j2] - mns);
      }
      float rs = (p0[0] + p0[1]) + (p0[2] + p0[3]) + (p1[0] + p1[1]) + (p1[2] + p1[3]);
      rs += __shfl_xor(rs, 16, 64);
      rs += __shfl_xor(rs, 32, 64);
      li += rs;
    } else {
      const float mn  = fmaxf(mi, tm);
      const float mns = fmaxf(mn, -1e30f);
#pragma unroll
      for (int j2 = 0; j2 < 4; j2++){
        p0[j2] = __expf(v0[j2] - mns);
        p1[j2] = __expf(v1[j2] - mns);
      }
      const float a_ = __expf(mi - mns);
      float rs = (p0[0] + p0[1]) + (p0[2] + p0[3]) + (p1[0] + p1[1]) + (p1[2] + p1[3]);
      rs += __shfl_xor(rs, 16, 64);
      rs += __shfl_xor(rs, 32, 64);
      li = li * a_ + rs;
      mi = mn;
      float av[4];
#pragma unroll
      for (int i = 0; i < 4; i++)
        av[i] = __shfl(a_, (lane & 48) | (lk * 4 + i), 64);
#pragma unroll
      for (int db = 0; db < 16; db++){
        f32x4 o = oacc[db];
#pragma unroll
        for (int i = 0; i < 4; i++) o[i] *= av[i];
        oacc[db] = o;
      }
    }

    const int w0 = cvtpk(p0[0], p0[1]), w1 = cvtpk(p0[2], p0[3]);
    const int w2 = cvtpk(p1[0], p1[1]), w3 = cvtpk(p1[2], p1[3]);
    const int sA = (((lk & 1) * 2) << 4) | lq;
    const int sB = sA + 16;
    const int a0 = __shfl(w0, sA, 64), a1 = __shfl(w1, sA, 64);
    const int b0 = __shfl(w0, sB, 64), b1 = __shfl(w1, sB, 64);
    const int c0w = __shfl(w2, sA, 64), c1w = __shfl(w3, sA, 64);
    const int d0w = __shfl(w2, sB, 64), d1w = __shfl(w3, sB, 64);
    const bool hi = (lk >= 2);
    I4B8 pau;
    pau.i.x = hi ? c0w : a0;
    pau.i.y = hi ? c1w : a1;
    pau.i.z = hi ? d0w : b0;
    pau.i.w = hi ? d1w : b1;

    const int vslot = (lk ^ ((lq >> 1) & 3)) << 3;
#pragma unroll
    for (int db = 0; db < 16; db++){
      bf16x8 vf = ld_bf8(&Vb[cur][(db * 16 + lq) * 32 + vslot]);
      oacc[db] = mfma16(pau.b, vf, oacc[db]);
    }

    __syncthreads();
    if (kt + 64 <= ktmax){ STAGE_K(cur, kt + 64); STAGE_V(cur, kt + 64); }
  }
#undef STAGE_K
#undef STAGE_V

#pragma unroll
  for (int i = 0; i < 4; i++){
    const float lf = __shfl(li, (lane & 48) | (lk * 4 + i), 64);
    const float inv = 1.0f / lf;
    unsigned short* orow = attnO + (size_t)(b * S_LEN + q0 + lk*4 + i) * QSZ + h * HD + lq;
#pragma unroll
    for (int db = 0; db < 16; db++)
      orow[db * 16] = f2bf(oacc[db][i] * inv);
  }
}

extern "C" void kernel_launch(void* const* d_in, const int* in_sizes, int n_in,
                              void* d_out, int out_size, void* d_ws, size_t ws_size,
                              hipStream_t stream)
{
  const int*   positions = (const int*)  d_in[0];
  const float* hidden    = (const float*)d_in[1];
  const int*   amask     = (const int*)  d_in[2];
  const float* Wqkv      = (const float*)d_in[3];
  const float* Wo        = (const float*)d_in[4];
  const float* qw        = (const float*)d_in[5];
  const float* kw        = (const float*)d_in[6];
  float* out = (float*)d_out;

  char* ws = (char*)d_ws;
  unsigned short* hB    = (unsigned short*)(ws);               // 4096x2560 bf16
  unsigned short* attnO = (unsigned short*)(ws);               // alias (4096x2048 bf16)
  unsigned short* WqT   = (unsigned short*)(ws + 20971520);    // [4096][2560] bf16
  unsigned short* WoT   = (unsigned short*)(ws + 41943040);    // [2560][2048] bf16
  unsigned short* qkvB  = (unsigned short*)(ws + 52428800);    // [4096][4096] bf16
  unsigned short* qb    = (unsigned short*)(ws + 119537664);   // [B][NH][S][HD]
  unsigned short* kb    = (unsigned short*)(ws + 136314880);   // [B][NKV][S][HD]
  unsigned short* vt    = (unsigned short*)(ws + 144703488);   // [B][NKV][HD][S]
  unsigned*       bm    = (unsigned*)     (ws + 153092096);   // [B][64] mask bits

  cast_bf16_kernel<<<dim3(MROWS * HIDDEN / 1024), 256, 0, stream>>>(hidden, hB, MROWS * HIDDEN);
  tcast_kernel<<<dim3(NQKV / 32, HIDDEN / 32), 256, 0, stream>>>(Wqkv, WqT, HIDDEN, NQKV);
  tcast_kernel<<<dim3(HIDDEN / 32, QSZ / 32), 256, 0, stream>>>(Wo, WoT, QSZ, HIDDEN);
  maskbits_kernel<<<dim3(1), 128, 0, stream>>>(amask, bm);

  // GEMM1: [4096 x 2560] * [2560 x 4096] -> qkvB (bf16); grid 256 blocks
  gemm256_kernel<1><<<dim3((MROWS/256) * (NQKV/256)), 512, 0, stream>>>(
      hB, WqT, qkvB, NQKV, HIDDEN, NQKV/256);

  normrope_kernel<<<dim3(S_LEN, BATCH), 256, 0, stream>>>(qkvB, positions, qw, kw, qb, kb, vt);

  attn_kernel<<<dim3(S_LEN / 32 * NKV * BATCH), 256, 0, stream>>>(qb, kb, vt, bm, attnO);

  // GEMM2: [4096 x 2048] * [2048 x 2560] -> out (f32); grid 160 blocks
  gemm256_kernel<0><<<dim3((MROWS/256) * (HIDDEN/256)), 512, 0, stream>>>(
      attnO, WoT, out, HIDDEN, QSZ, HIDDEN/256);
}

// Round 8
// 338.479 us; speedup vs baseline: 1.1420x; 1.1420x over previous
//
#include <hip/hip_runtime.h>
#include <stdint.h>

#define S_LEN 2048
#define BATCH 2
#define HIDDEN 2560
#define NH 8
#define NKV 4
#define HD 256
#define QSZ (NH*HD)          // 2048
#define NQKV 4096            // QSZ + 2*KVSZ
#define MROWS (BATCH*S_LEN)  // 4096
#define SCALE_ATT 0.0625f

using bf16x8 = __attribute__((__ext_vector_type__(8))) __bf16;
using f32x4  = __attribute__((__ext_vector_type__(4))) float;
using s16x8  = __attribute__((__ext_vector_type__(8))) short;

union B8u { s16x8 s; bf16x8 b; };
union I4B8 { int4 i; bf16x8 b; };

__device__ __forceinline__ unsigned short f2bf(float x){
  unsigned u = __float_as_uint(x);
  u += 0x7fffu + ((u >> 16) & 1u);
  return (unsigned short)(u >> 16);
}
__device__ __forceinline__ float bf2f(unsigned short h){
  return __uint_as_float(((unsigned)h) << 16);
}
__device__ __forceinline__ bf16x8 ld_bf8(const unsigned short* p){
  B8u u; u.s = *reinterpret_cast<const s16x8*>(p); return u.b;
}
__device__ __forceinline__ f32x4 mfma16(bf16x8 a, bf16x8 b, f32x4 c){
  return __builtin_amdgcn_mfma_f32_16x16x32_bf16(a, b, c, 0, 0, 0);
}
__device__ __forceinline__ void gload16(const void* g, void* l){
  __builtin_amdgcn_global_load_lds((const __attribute__((address_space(1))) void*)g,
                                   (__attribute__((address_space(3))) void*)l,
                                   16, 0, 0);
}
__device__ __forceinline__ int cvtpk(float lo, float hi){
  int r;
  asm("v_cvt_pk_bf16_f32 %0, %1, %2" : "=v"(r) : "v"(lo), "v"(hi));
  return r;
}

// ---------------- cast fp32 -> bf16 (flat) ----------------
__global__ __launch_bounds__(256) void cast_bf16_kernel(
    const float* __restrict__ in, unsigned short* __restrict__ out, int n)
{
  int i = (blockIdx.x * 256 + threadIdx.x) * 4;
  if (i < n){
    float4 v = *reinterpret_cast<const float4*>(in + i);
    ushort4 o;
    o.x = f2bf(v.x); o.y = f2bf(v.y); o.z = f2bf(v.z); o.w = f2bf(v.w);
    *reinterpret_cast<ushort4*>(out + i) = o;
  }
}

// ---------------- transpose + cast: in[R][C] fp32 -> out[C][R] bf16 ----------------
__global__ __launch_bounds__(256) void tcast_kernel(
    const float* __restrict__ in, unsigned short* __restrict__ out, int R, int C)
{
  __shared__ float t[32][33];
  int c0 = blockIdx.x * 32, r0 = blockIdx.y * 32;
  int tx = threadIdx.x & 31, ty = threadIdx.x >> 5;
#pragma unroll
  for (int ii = 0; ii < 4; ii++)
    t[ty + ii*8][tx] = in[(size_t)(r0 + ty + ii*8) * C + c0 + tx];
  __syncthreads();
#pragma unroll
  for (int ii = 0; ii < 4; ii++)
    out[(size_t)(c0 + ty + ii*8) * R + r0 + tx] = f2bf(t[tx][ty + ii*8]);
}

// ================= 256x256 8-wave deep-pipelined GEMM (T2+T3+T4+T5) =================
template<int BF16OUT>
__global__ __launch_bounds__(512, 2) void gemm256_kernel(
    const unsigned short* __restrict__ A,
    const unsigned short* __restrict__ BT,
    void* __restrict__ Cv,
    int N, int K, int nbn)
{
  __shared__ unsigned short Ab[2][256 * 64];
  __shared__ unsigned short Bb[2][256 * 64];

  const int tid  = threadIdx.x;
  const int lane = tid & 63;
  const int wid  = tid >> 6;            // 0..7
  const int wm = wid >> 2, wn = wid & 3;
  const int lq = lane & 15, lk = lane >> 4;

  const int cpx = gridDim.x >> 3;
  const int wg  = (blockIdx.x & 7) * cpx + (blockIdx.x >> 3);
  const int bm = wg / nbn, bn = wg % nbn;

  const int l8 = lane >> 3;
  const int sl = ((lane & 7) ^ l8) * 8;
  const unsigned short* agS = A  + (size_t)(bm*256 + wid*16 + l8) * K + sl;
  const unsigned short* bgS = BT + (size_t)(bn*256 + wid*16 + l8) * K + sl;

  f32x4 acc[4][4][2] = {};
  bf16x8 a[4][2], b[2][2];

#define STA(c, h, tt) do {                                                    \
    unsigned short* d = &Ab[c][(h)*8192 + wid*1024];                          \
    const unsigned short* s = agS + (size_t)(h)*128*K + (size_t)(tt)*64;      \
    gload16(s, d); gload16(s + 8*(size_t)K, d + 512);                         \
  } while (0)
#define STB(c, h, tt) do {                                                    \
    unsigned short* d = &Bb[c][(h)*8192 + wid*1024];                          \
    const unsigned short* s = bgS + (size_t)(h)*128*K + (size_t)(tt)*64;      \
    gload16(s, d); gload16(s + 8*(size_t)K, d + 512);                         \
  } while (0)
#define LDA(qa) do {                                                          \
    _Pragma("unroll") for (int m = 0; m < 4; m++)                             \
    _Pragma("unroll") for (int kk = 0; kk < 2; kk++)                          \
      a[m][kk] = ld_bf8(&Ab[cur][((qa)*128 + wm*64 + m*16 + lq)*64            \
                                 + (((kk*4 + lk) ^ (lq & 7)) << 3)]);         \
  } while (0)
#define LDB(qb) do {                                                          \
    _Pragma("unroll") for (int n = 0; n < 2; n++)                             \
    _Pragma("unroll") for (int kk = 0; kk < 2; kk++)                          \
      b[n][kk] = ld_bf8(&Bb[cur][((qb)*128 + wn*32 + n*16 + lq)*64            \
                                 + (((kk*4 + lk) ^ (lq & 7)) << 3)]);         \
  } while (0)
#define MM(qi) do {                                                           \
    __builtin_amdgcn_s_setprio(1);                                            \
    _Pragma("unroll") for (int m = 0; m < 4; m++)                             \
    _Pragma("unroll") for (int n = 0; n < 2; n++)                             \
    _Pragma("unroll") for (int kk = 0; kk < 2; kk++)                          \
      acc[qi][m][n] = mfma16(a[m][kk], b[n][kk], acc[qi][m][n]);              \
    __builtin_amdgcn_s_setprio(0);                                            \
  } while (0)
#define BARR __builtin_amdgcn_s_barrier()
#define VM(n) asm volatile("s_waitcnt vmcnt(" #n ")" ::: "memory")

  STA(0, 0, 0); STB(0, 0, 0); STB(0, 1, 0); STA(0, 1, 0);
  VM(4); BARR;

  const int NT = K >> 6;
  for (int t = 0; t < NT - 1; ++t){
    const int cur = t & 1, nxt = cur ^ 1;
    LDA(0); LDB(0); STA(nxt, 0, t+1);
    BARR; MM(0); VM(4); BARR;
    LDB(1);         STB(nxt, 0, t+1);
    BARR; MM(1); VM(4); BARR;
    LDA(1);         STB(nxt, 1, t+1);
    BARR; MM(2);        BARR;
    LDB(0);         STA(nxt, 1, t+1);
    BARR; MM(3); VM(4); BARR;
  }
  {
    const int cur = (NT - 1) & 1;
    LDA(0); LDB(0); BARR; MM(0); VM(2); BARR;
    LDB(1);         BARR; MM(1); VM(0); BARR;
    LDA(1);         BARR; MM(2);        BARR;
    LDB(0);         BARR; MM(3);        BARR;
  }
#undef STA
#undef STB
#undef LDA
#undef LDB
#undef MM
#undef BARR
#undef VM

#pragma unroll
  for (int qi = 0; qi < 4; qi++){
    const int qa = qi >> 1;
    const int qb = (qi ^ (qi >> 1)) & 1;
    const int r0 = bm*256 + qa*128 + wm*64;
    const int c0 = bn*256 + qb*128 + wn*32;
#pragma unroll
    for (int m = 0; m < 4; m++)
#pragma unroll
      for (int n = 0; n < 2; n++)
#pragma unroll
        for (int i = 0; i < 4; i++){
          const size_t idx = (size_t)(r0 + m*16 + lk*4 + i) * N + (c0 + n*16 + lq);
          if (BF16OUT) ((unsigned short*)Cv)[idx] = f2bf(acc[qi][m][n][i]);
          else         ((float*)Cv)[idx]          = acc[qi][m][n][i];
        }
  }
}

// ---------------- RMSNorm + RoPE + scatter to q/k/vT (qkv bf16) ----------------
__global__ __launch_bounds__(256) void normrope_kernel(
    const unsigned short* __restrict__ qkv,
    const int* __restrict__ positions,
    const float* __restrict__ qw, const float* __restrict__ kw,
    unsigned short* __restrict__ qB,
    unsigned short* __restrict__ kB,
    unsigned short* __restrict__ vT)
{
  const int s = blockIdx.x, b = blockIdx.y;
  const int lane = threadIdx.x & 63, wid = threadIdx.x >> 6;
  const unsigned short* row = qkv + (size_t)(b * S_LEN + s) * NQKV;
  const float fpos = (float)positions[b * S_LEN + s];

#pragma unroll
  for (int t = 0; t < 4; t++){
    const int seg = t * 4 + wid;
    const int base = seg * HD;
    float x0 = bf2f(row[base + lane]);
    float x1 = bf2f(row[base + lane + 64]);
    float x2 = bf2f(row[base + lane + 128]);
    float x3 = bf2f(row[base + lane + 192]);
    if (seg >= 12){
      const int mh = seg - 12;
      unsigned short* vb = vT + (size_t)(b * NKV + mh) * HD * S_LEN + s;
      vb[(size_t)(lane      ) * S_LEN] = f2bf(x0);
      vb[(size_t)(lane +  64) * S_LEN] = f2bf(x1);
      vb[(size_t)(lane + 128) * S_LEN] = f2bf(x2);
      vb[(size_t)(lane + 192) * S_LEN] = f2bf(x3);
    } else {
      const float* w = (seg < 8) ? qw : kw;
      float ssq = x0*x0 + x1*x1 + x2*x2 + x3*x3;
#pragma unroll
      for (int d = 1; d < 64; d <<= 1) ssq += __shfl_xor(ssq, d, 64);
      float rs = rsqrtf(ssq * (1.0f / 256.0f) + 1e-6f);
      float y0 = x0 * rs * (1.0f + w[lane]);
      float y1 = x1 * rs * (1.0f + w[lane + 64]);
      float y2 = x2 * rs * (1.0f + w[lane + 128]);
      float y3 = x3 * rs * (1.0f + w[lane + 192]);
      const float kln = -9.210340371976184f / 128.0f;
      float inv1 = expf((float)lane * kln);
      float inv2 = expf((float)(lane + 64) * kln);
      float s1, c1, s2, c2;
      sincosf(fpos * inv1, &s1, &c1);
      sincosf(fpos * inv2, &s2, &c2);
      float o0 = y0 * c1 - y2 * s1;
      float o2 = y2 * c1 + y0 * s1;
      float o1 = y1 * c2 - y3 * s2;
      float o3 = y3 * c2 + y1 * s2;
      unsigned short* dst = (seg < 8)
        ? qB + ((size_t)(b * NH  +  seg     ) * S_LEN + s) * HD
        : kB + ((size_t)(b * NKV + (seg - 8)) * S_LEN + s) * HD;
      dst[lane      ] = f2bf(o0);
      dst[lane +  64] = f2bf(o1);
      dst[lane + 128] = f2bf(o2);
      dst[lane + 192] = f2bf(o3);
    }
  }
}

// ---------------- mask bit pack + work-queue counter reset ----------------
__global__ void maskbits_kernel(const int* __restrict__ amask, unsigned* __restrict__ bm,
                                int* __restrict__ ctr)
{
  int t = threadIdx.x;                 // 0..127
  int b = t >> 6, tile = t & 63;
  unsigned m = 0;
  for (int j = 0; j < 32; j++)
    m |= (amask[b * S_LEN + tile * 32 + j] != 0 ? 1u : 0u) << j;
  bm[t] = m;
  if (t < 8) ctr[t] = 0;
}

// ---------------- flash attention v7: persistent blocks + per-combo work queue ----------------
// Grid 256 (1 block/CU). combo c = blockIdx.x & 7 (id%8 -> XCD round-robin, R5-confirmed)
// fixes (mh, b); 32 workers per combo pop q-tiles heavy-first from an atomic queue ->
// load balance independent of the (opaque) block->CU dispatch policy.
__global__ __launch_bounds__(256) void attn_kernel(
    const unsigned short* __restrict__ qB,
    const unsigned short* __restrict__ kB,
    const unsigned short* __restrict__ vT,
    const unsigned* __restrict__ bmG,
    unsigned short* __restrict__ attnO,
    int* __restrict__ ctr)
{
  __shared__ unsigned short Kb[2][32 * 256];
  __shared__ unsigned short Vb[2][256 * 32];
  __shared__ unsigned bm_lds[64];
  __shared__ int s_idx;

  const int tid  = threadIdx.x;
  const int lane = tid & 63, wid = tid >> 6;
  const int c  = blockIdx.x & 7;
  const int mh = c & 3, b = c >> 2;
  const int h  = mh * 2 + (wid >> 1);
  const int lq = lane & 15, lk = lane >> 4;

  if (tid < 64) bm_lds[tid] = bmG[(b << 6) + tid];

  const unsigned short* kbase = kB + (size_t)(b * NKV + mh) * S_LEN * HD;
  const unsigned short* vbase = vT + (size_t)(b * NKV + mh) * HD * S_LEN;
  const int krow0 = wid * 2 + (lane >> 5);
  const int kgsrc = (lane & 31) ^ (krow0 & 7);
  const unsigned short* kg0 = kbase + (size_t)krow0 * HD + kgsrc * 8;
  const int vd0 = wid * 16 + (lane >> 2);
  const int vgsrc = (lane & 3) ^ ((lane >> 3) & 3);
  const unsigned short* vg0 = vbase + (size_t)vd0 * S_LEN + vgsrc * 8;

#define STAGE_K(buf, ktv)                                                      \
  do {                                                                         \
    _Pragma("unroll")                                                          \
    for (int r = 0; r < 4; r++)                                                \
      gload16(kg0 + (size_t)(ktv) * HD + r * (8 * HD),                         \
              &Kb[buf][wid * 512 + r * 2048]);                                 \
  } while (0)
#define STAGE_V(buf, ktv)                                                      \
  do {                                                                         \
    _Pragma("unroll")                                                          \
    for (int r = 0; r < 4; r++)                                                \
      gload16(vg0 + (ktv) + (size_t)r * (64 * S_LEN),                          \
              &Vb[buf][wid * 512 + r * 2048]);                                 \
  } while (0)

  for (;;){
    if (tid == 0) s_idx = atomicAdd(&ctr[c], 1);
    __syncthreads();
    const int idx = s_idx;
    __syncthreads();
    if (idx >= 64) break;
    const int qt = 63 - idx;                     // heavy-first

    const int q0 = qt * 32 + (wid & 1) * 16;
    const int q  = q0 + lq;

    const unsigned short* qbase = qB + ((size_t)(b * NH + h) * S_LEN + q0 + lq) * HD + lk * 8;
    bf16x8 aq[8];
#pragma unroll
    for (int ks = 0; ks < 8; ks++) aq[ks] = ld_bf8(qbase + ks * 32);
    asm volatile("s_waitcnt vmcnt(0)" ::: "memory");

    float mi = -__builtin_inff(), li = 0.f;
    f32x4 oacc[16] = {};

    const int ktmax = qt * 32;

    STAGE_K(0, 0);  STAGE_V(0, 0);
    if (ktmax >= 32){ STAGE_K(1, 32); STAGE_V(1, 32); }

    int cur = 0;
    for (int kt = 0; kt <= ktmax; kt += 32, cur ^= 1){
      if (kt < ktmax) asm volatile("s_waitcnt vmcnt(8)" ::: "memory");
      else            asm volatile("s_waitcnt vmcnt(0)" ::: "memory");
      __syncthreads();                                   // (A) cur K+V published

      f32x4 s0 = {0.f,0.f,0.f,0.f}, s1 = {0.f,0.f,0.f,0.f};
#pragma unroll
      for (int ks = 0; ks < 8; ks++){
        const int slot = (((ks * 4 + lk) ^ (lq & 7)) << 3);
        bf16x8 kf0 = ld_bf8(&Kb[cur][lq * 256 + slot]);
        bf16x8 kf1 = ld_bf8(&Kb[cur][(16 + lq) * 256 + slot]);
        s0 = mfma16(kf0, aq[ks], s0);
        s1 = mfma16(kf1, aq[ks], s1);
      }

      const unsigned mask32 = bm_lds[kt >> 5];
      const int koff = lk * 4;
      float v0[4], v1[4];
#pragma unroll
      for (int j2 = 0; j2 < 4; j2++){
        const bool cc0 = (kt + koff + j2 <= q)      && ((mask32 >> (koff + j2)) & 1u);
        const bool cc1 = (kt + 16 + koff + j2 <= q) && ((mask32 >> (16 + koff + j2)) & 1u);
        v0[j2] = cc0 ? s0[j2] * SCALE_ATT : -__builtin_inff();
        v1[j2] = cc1 ? s1[j2] * SCALE_ATT : -__builtin_inff();
      }
      float tm = fmaxf(fmaxf(fmaxf(v0[0], v0[1]), fmaxf(v0[2], v0[3])),
                       fmaxf(fmaxf(v1[0], v1[1]), fmaxf(v1[2], v1[3])));
      tm = fmaxf(tm, __shfl_xor(tm, 16, 64));
      tm = fmaxf(tm, __shfl_xor(tm, 32, 64));

      float p0[4], p1[4];
      if (__all(tm <= mi + 8.0f)){
        const float mns = fmaxf(mi, -1e30f);
#pragma unroll
        for (int j2 = 0; j2 < 4; j2++){
          p0[j2] = __expf(v0[j2] - mns);
          p1[j2] = __expf(v1[j2] - mns);
        }
        float rs = (p0[0] + p0[1]) + (p0[2] + p0[3]) + (p1[0] + p1[1]) + (p1[2] + p1[3]);
        rs += __shfl_xor(rs, 16, 64);
        rs += __shfl_xor(rs, 32, 64);
        li += rs;
      } else {
        const float mn  = fmaxf(mi, tm);
        const float mns = fmaxf(mn, -1e30f);
#pragma unroll
        for (int j2 = 0; j2 < 4; j2++){
          p0[j2] = __expf(v0[j2] - mns);
          p1[j2] = __expf(v1[j2] - mns);
        }
        const float a_ = __expf(mi - mns);
        float rs = (p0[0] + p0[1]) + (p0[2] + p0[3]) + (p1[0] + p1[1]) + (p1[2] + p1[3]);
        rs += __shfl_xor(rs, 16, 64);
        rs += __shfl_xor(rs, 32, 64);
        li = li * a_ + rs;
        mi = mn;
        float av[4];
#pragma unroll
        for (int i = 0; i < 4; i++)
          av[i] = __shfl(a_, (lane & 48) | (lk * 4 + i), 64);
#pragma unroll
        for (int db = 0; db < 16; db++){
          f32x4 o = oacc[db];
#pragma unroll
          for (int i = 0; i < 4; i++) o[i] *= av[i];
          oacc[db] = o;
        }
      }

      const int w0 = cvtpk(p0[0], p0[1]), w1 = cvtpk(p0[2], p0[3]);
      const int w2 = cvtpk(p1[0], p1[1]), w3 = cvtpk(p1[2], p1[3]);
      const int sA = (((lk & 1) * 2) << 4) | lq;
      const int sB = sA + 16;
      const int a0 = __shfl(w0, sA, 64), a1 = __shfl(w1, sA, 64);
      const int b0 = __shfl(w0, sB, 64), b1 = __shfl(w1, sB, 64);
      const int c0w = __shfl(w2, sA, 64), c1w = __shfl(w3, sA, 64);
      const int d0w = __shfl(w2, sB, 64), d1w = __shfl(w3, sB, 64);
      const bool hi = (lk >= 2);
      I4B8 pau;
      pau.i.x = hi ? c0w : a0;
      pau.i.y = hi ? c1w : a1;
      pau.i.z = hi ? d0w : b0;
      pau.i.w = hi ? d1w : b1;

      const int vslot = (lk ^ ((lq >> 1) & 3)) << 3;
#pragma unroll
      for (int db = 0; db < 16; db++){
        bf16x8 vf = ld_bf8(&Vb[cur][(db * 16 + lq) * 32 + vslot]);
        oacc[db] = mfma16(pau.b, vf, oacc[db]);
      }

      __syncthreads();                                   // (B) all waves done reading cur
      if (kt + 64 <= ktmax){ STAGE_K(cur, kt + 64); STAGE_V(cur, kt + 64); }
    }

#pragma unroll
    for (int i = 0; i < 4; i++){
      const float lf = __shfl(li, (lane & 48) | (lk * 4 + i), 64);
      const float inv = 1.0f / lf;
      unsigned short* orow = attnO + (size_t)(b * S_LEN + q0 + lk*4 + i) * QSZ + h * HD + lq;
#pragma unroll
      for (int db = 0; db < 16; db++)
        orow[db * 16] = f2bf(oacc[db][i] * inv);
    }
  }
#undef STAGE_K
#undef STAGE_V
}

extern "C" void kernel_launch(void* const* d_in, const int* in_sizes, int n_in,
                              void* d_out, int out_size, void* d_ws, size_t ws_size,
                              hipStream_t stream)
{
  const int*   positions = (const int*)  d_in[0];
  const float* hidden    = (const float*)d_in[1];
  const int*   amask     = (const int*)  d_in[2];
  const float* Wqkv      = (const float*)d_in[3];
  const float* Wo        = (const float*)d_in[4];
  const float* qw        = (const float*)d_in[5];
  const float* kw        = (const float*)d_in[6];
  float* out = (float*)d_out;

  char* ws = (char*)d_ws;
  unsigned short* hB    = (unsigned short*)(ws);               // 4096x2560 bf16
  unsigned short* attnO = (unsigned short*)(ws);               // alias (4096x2048 bf16)
  unsigned short* WqT   = (unsigned short*)(ws + 20971520);    // [4096][2560] bf16
  unsigned short* WoT   = (unsigned short*)(ws + 41943040);    // [2560][2048] bf16
  unsigned short* qkvB  = (unsigned short*)(ws + 52428800);    // [4096][4096] bf16
  unsigned short* qb    = (unsigned short*)(ws + 119537664);   // [B][NH][S][HD]
  unsigned short* kb    = (unsigned short*)(ws + 136314880);   // [B][NKV][S][HD]
  unsigned short* vt    = (unsigned short*)(ws + 144703488);   // [B][NKV][HD][S]
  unsigned*       bm    = (unsigned*)     (ws + 153092096);   // [B][64] mask bits
  int*            ctr   = (int*)          (ws + 153092608);   // [8] work-queue counters

  cast_bf16_kernel<<<dim3(MROWS * HIDDEN / 1024), 256, 0, stream>>>(hidden, hB, MROWS * HIDDEN);
  tcast_kernel<<<dim3(NQKV / 32, HIDDEN / 32), 256, 0, stream>>>(Wqkv, WqT, HIDDEN, NQKV);
  tcast_kernel<<<dim3(HIDDEN / 32, QSZ / 32), 256, 0, stream>>>(Wo, WoT, QSZ, HIDDEN);
  maskbits_kernel<<<dim3(1), 128, 0, stream>>>(amask, bm, ctr);

  // GEMM1: [4096 x 2560] * [2560 x 4096] -> qkvB (bf16); grid 256 blocks
  gemm256_kernel<1><<<dim3((MROWS/256) * (NQKV/256)), 512, 0, stream>>>(
      hB, WqT, qkvB, NQKV, HIDDEN, NQKV/256);

  normrope_kernel<<<dim3(S_LEN, BATCH), 256, 0, stream>>>(qkvB, positions, qw, kw, qb, kb, vt);

  attn_kernel<<<dim3(256), 256, 0, stream>>>(qb, kb, vt, bm, attnO, ctr);

  // GEMM2: [4096 x 2048] * [2048 x 2560] -> out (f32); grid 160 blocks
  gemm256_kernel<0><<<dim3((MROWS/256) * (HIDDEN/256)), 512, 0, stream>>>(
      attnO, WoT, out, HIDDEN, QSZ, HIDDEN/256);
}